// Round 1
// 155.075 us; speedup vs baseline: 1.0357x; 1.0357x over previous
//
#include <hip/hip_runtime.h>
#include <math.h>

#define N_PTS 1024
#define HID   256
#define FEAT  2048

typedef short bf16x8 __attribute__((ext_vector_type(8)));
typedef float f32x4  __attribute__((ext_vector_type(4)));

__device__ inline ushort f2bf(float f) {
    union { float f; unsigned u; } v; v.f = f;
    unsigned r = v.u + 0x7fff + ((v.u >> 16) & 1);   // round-to-nearest-even
    return (ushort)(r >> 16);
}

// ---------------- bf16 MFMA GEMM: C += A@B (atomic fp32 epilogue) ----------
// A fp32 [M][lda] row-major, B fp32 [K][ldb] row-major, C fp32 [.][ldc].
// 64x64 tile, BK=64, 256 threads (4 waves in 2x2), split-K over blockIdx.z.
__global__ __launch_bounds__(256) void gemm_mfma(
    const float* __restrict__ A, const float* __restrict__ B,
    float* __restrict__ C, int lda, int ldb, int ldc, int kchunk)
{
    __shared__ ushort As[64 * 72];
    __shared__ ushort Bs[64 * 72];
    const int tid  = threadIdx.x;
    const int lane = tid & 63;
    const int wave = tid >> 6;
    const int wy = wave >> 1, wx = wave & 1;
    const int quad = lane >> 4, l16 = lane & 15;
    const int mBase = blockIdx.y * 64;
    const int nBase = blockIdx.x * 64;
    const int kBeg  = blockIdx.z * kchunk;

    f32x4 acc[2][2] = {};

    for (int ks = kBeg; ks < kBeg + kchunk; ks += 64) {
        #pragma unroll
        for (int p = 0; p < 4; p++) {
            const int c  = p * 256 + tid;
            const int r  = c >> 4;
            const int cq = c & 15;
            float4 av = *(const float4*)&A[(size_t)(mBase + r) * lda + ks + cq * 4];
            ushort4 ao;
            ao.x = f2bf(av.x); ao.y = f2bf(av.y);
            ao.z = f2bf(av.z); ao.w = f2bf(av.w);
            *(ushort4*)&As[r * 72 + cq * 4] = ao;
            float4 bv = *(const float4*)&B[(size_t)(ks + r) * ldb + nBase + cq * 4];
            Bs[(cq * 4 + 0) * 72 + r] = f2bf(bv.x);
            Bs[(cq * 4 + 1) * 72 + r] = f2bf(bv.y);
            Bs[(cq * 4 + 2) * 72 + r] = f2bf(bv.z);
            Bs[(cq * 4 + 3) * 72 + r] = f2bf(bv.w);
        }
        __syncthreads();
        #pragma unroll
        for (int kt = 0; kt < 64; kt += 32) {
            bf16x8 af[2], bfr[2];
            #pragma unroll
            for (int mi = 0; mi < 2; mi++)
                af[mi] = *(bf16x8*)&As[(wy * 32 + mi * 16 + l16) * 72 + kt + quad * 8];
            #pragma unroll
            for (int ni = 0; ni < 2; ni++)
                bfr[ni] = *(bf16x8*)&Bs[(wx * 32 + ni * 16 + l16) * 72 + kt + quad * 8];
            #pragma unroll
            for (int mi = 0; mi < 2; mi++)
                #pragma unroll
                for (int ni = 0; ni < 2; ni++)
                    acc[mi][ni] = __builtin_amdgcn_mfma_f32_16x16x32_bf16(
                        af[mi], bfr[ni], acc[mi][ni], 0, 0, 0);
        }
        __syncthreads();
    }
    #pragma unroll
    for (int mi = 0; mi < 2; mi++)
        #pragma unroll
        for (int ni = 0; ni < 2; ni++)
            #pragma unroll
            for (int e = 0; e < 4; e++) {
                const int gm = mBase + wy * 32 + mi * 16 + quad * 4 + e;
                const int gn = nBase + wx * 32 + ni * 16 + l16;
                unsafeAtomicAdd(&C[(size_t)gm * ldc + gn], acc[mi][ni][e]);
            }
}

// ---------------- per-column sum / sumsq for x1 (atomic partials) ----------
__global__ __launch_bounds__(256) void colstats(
    const float* __restrict__ X, float* __restrict__ sum,
    float* __restrict__ sq, int rowsPerBlock)
{
    const int c = threadIdx.x;
    const int r0 = blockIdx.x * rowsPerBlock;
    float s = 0.f, q = 0.f;
    for (int r = r0; r < r0 + rowsPerBlock; ++r) {
        float v = X[r * HID + c];
        s += v;
        q = fmaf(v, v, q);
    }
    unsafeAtomicAdd(&sum[c], s);
    unsafeAtomicAdd(&sq[c], q);
}

// ---------------- BN (train-mode) + ReLU (layer 2 only now) ----------------
__global__ __launch_bounds__(256) void bn_relu(
    const float* __restrict__ X, const float* __restrict__ sum,
    const float* __restrict__ sq, const float* __restrict__ g,
    const float* __restrict__ bt, float* __restrict__ Y)
{
    const int idx = blockIdx.x * 256 + threadIdx.x;
    const int cq = (idx & 63) * 4;
    float4 x = ((const float4*)X)[idx];
    float xv[4] = {x.x, x.y, x.z, x.w};
    float o[4];
    #pragma unroll
    for (int e = 0; e < 4; e++) {
        const int c = cq + e;
        float m   = sum[c] * (1.f / 1024.f);
        float var = fmaf(-m, m, sq[c] * (1.f / 1024.f));
        float rstd = rsqrtf(var + 1e-5f);
        o[e] = fmaxf(fmaf(g[c] * rstd, xv[e] - m, bt[c]), 0.f);
    }
    ((float4*)Y)[idx] = make_float4(o[0], o[1], o[2], o[3]);
}

// ---- layer2 GEMM, split-K=1: BN1+ReLU fused into A-staging, colstats2
// ---- fused into epilogue (plain stores, no atomics on C).
__global__ __launch_bounds__(256) void gemm2_fused(
    const float* __restrict__ A /*x1*/, const float* __restrict__ B /*W2*/,
    float* __restrict__ C /*x2*/,
    const float* __restrict__ sum1, const float* __restrict__ sq1,
    const float* __restrict__ g1, const float* __restrict__ bt1,
    float* __restrict__ sum2, float* __restrict__ sq2)
{
    __shared__ ushort As[64 * 72];
    __shared__ ushort Bs[64 * 72];
    __shared__ float sscale[HID];
    __shared__ float sshift[HID];
    __shared__ float csum[64];
    __shared__ float csq[64];
    const int tid  = threadIdx.x;
    const int lane = tid & 63;
    const int wave = tid >> 6;
    const int wy = wave >> 1, wx = wave & 1;
    const int quad = lane >> 4, l16 = lane & 15;
    const int mBase = blockIdx.y * 64;
    const int nBase = blockIdx.x * 64;

    // BN1 scale/shift from stats1: relu(sc*x + sh)
    {
        float m   = sum1[tid] * (1.f / 1024.f);
        float var = fmaf(-m, m, sq1[tid] * (1.f / 1024.f));
        float rstd = rsqrtf(var + 1e-5f);
        float sc = g1[tid] * rstd;
        sscale[tid] = sc;
        sshift[tid] = fmaf(-m, sc, bt1[tid]);
    }
    if (tid < 64) { csum[tid] = 0.f; csq[tid] = 0.f; }
    __syncthreads();

    f32x4 acc[2][2] = {};
    for (int ks = 0; ks < HID; ks += 64) {
        #pragma unroll
        for (int p = 0; p < 4; p++) {
            const int c  = p * 256 + tid;
            const int r  = c >> 4;
            const int cq = c & 15;
            const int k0 = ks + cq * 4;
            float4 av = *(const float4*)&A[(size_t)(mBase + r) * HID + k0];
            float v0 = fmaxf(fmaf(sscale[k0 + 0], av.x, sshift[k0 + 0]), 0.f);
            float v1 = fmaxf(fmaf(sscale[k0 + 1], av.y, sshift[k0 + 1]), 0.f);
            float v2 = fmaxf(fmaf(sscale[k0 + 2], av.z, sshift[k0 + 2]), 0.f);
            float v3 = fmaxf(fmaf(sscale[k0 + 3], av.w, sshift[k0 + 3]), 0.f);
            ushort4 ao;
            ao.x = f2bf(v0); ao.y = f2bf(v1); ao.z = f2bf(v2); ao.w = f2bf(v3);
            *(ushort4*)&As[r * 72 + cq * 4] = ao;
            float4 bv = *(const float4*)&B[(size_t)(ks + r) * HID + nBase + cq * 4];
            Bs[(cq * 4 + 0) * 72 + r] = f2bf(bv.x);
            Bs[(cq * 4 + 1) * 72 + r] = f2bf(bv.y);
            Bs[(cq * 4 + 2) * 72 + r] = f2bf(bv.z);
            Bs[(cq * 4 + 3) * 72 + r] = f2bf(bv.w);
        }
        __syncthreads();
        #pragma unroll
        for (int kt = 0; kt < 64; kt += 32) {
            bf16x8 af[2], bfr[2];
            #pragma unroll
            for (int mi = 0; mi < 2; mi++)
                af[mi] = *(bf16x8*)&As[(wy * 32 + mi * 16 + l16) * 72 + kt + quad * 8];
            #pragma unroll
            for (int ni = 0; ni < 2; ni++)
                bfr[ni] = *(bf16x8*)&Bs[(wx * 32 + ni * 16 + l16) * 72 + kt + quad * 8];
            #pragma unroll
            for (int mi = 0; mi < 2; mi++)
                #pragma unroll
                for (int ni = 0; ni < 2; ni++)
                    acc[mi][ni] = __builtin_amdgcn_mfma_f32_16x16x32_bf16(
                        af[mi], bfr[ni], acc[mi][ni], 0, 0, 0);
        }
        __syncthreads();
    }

    // epilogue: plain store + fused column stats (full K done, no split-K)
    float s[2] = {0.f, 0.f}, q[2] = {0.f, 0.f};
    #pragma unroll
    for (int mi = 0; mi < 2; mi++)
        #pragma unroll
        for (int ni = 0; ni < 2; ni++)
            #pragma unroll
            for (int e = 0; e < 4; e++) {
                const int gm = mBase + wy * 32 + mi * 16 + quad * 4 + e;
                const int gn = nBase + wx * 32 + ni * 16 + l16;
                float v = acc[mi][ni][e];
                C[(size_t)gm * HID + gn] = v;
                s[ni] += v;
                q[ni] = fmaf(v, v, q[ni]);
            }
    #pragma unroll
    for (int ni = 0; ni < 2; ni++) {
        float sv = s[ni], qv = q[ni];
        sv += __shfl_xor(sv, 16, 64); sv += __shfl_xor(sv, 32, 64);
        qv += __shfl_xor(qv, 16, 64); qv += __shfl_xor(qv, 32, 64);
        if (quad == 0) {                       // one lane per (wave, l16)
            atomicAdd(&csum[wx * 32 + ni * 16 + l16], sv);
            atomicAdd(&csq [wx * 32 + ni * 16 + l16], qv);
        }
    }
    __syncthreads();
    if (tid < 64) {
        unsafeAtomicAdd(&sum2[nBase + tid], csum[tid]);
        unsafeAtomicAdd(&sq2 [nBase + tid], csq[tid]);
    }
}

// ---- merged edge-net GEMMs: z<4 -> hi = di@We1[:H], z>=4 -> hj = di@We1[H:]
__global__ __launch_bounds__(256) void gemm_dual(
    const float* __restrict__ A, const float* __restrict__ B1,
    const float* __restrict__ B2, float* __restrict__ C1, float* __restrict__ C2)
{
    __shared__ ushort As[64 * 72];
    __shared__ ushort Bs[64 * 72];
    const int tid  = threadIdx.x;
    const int lane = tid & 63;
    const int wave = tid >> 6;
    const int wy = wave >> 1, wx = wave & 1;
    const int quad = lane >> 4, l16 = lane & 15;
    const int mBase = blockIdx.y * 64;
    const int nBase = blockIdx.x * 64;
    const float* B = (blockIdx.z >= 4) ? B2 : B1;
    float*       C = (blockIdx.z >= 4) ? C2 : C1;
    const int ks = (blockIdx.z & 3) * 64;

    f32x4 acc[2][2] = {};
    #pragma unroll
    for (int p = 0; p < 4; p++) {
        const int c  = p * 256 + tid;
        const int r  = c >> 4;
        const int cq = c & 15;
        float4 av = *(const float4*)&A[(size_t)(mBase + r) * HID + ks + cq * 4];
        ushort4 ao;
        ao.x = f2bf(av.x); ao.y = f2bf(av.y);
        ao.z = f2bf(av.z); ao.w = f2bf(av.w);
        *(ushort4*)&As[r * 72 + cq * 4] = ao;
        float4 bv = *(const float4*)&B[(size_t)(ks + r) * HID + nBase + cq * 4];
        Bs[(cq * 4 + 0) * 72 + r] = f2bf(bv.x);
        Bs[(cq * 4 + 1) * 72 + r] = f2bf(bv.y);
        Bs[(cq * 4 + 2) * 72 + r] = f2bf(bv.z);
        Bs[(cq * 4 + 3) * 72 + r] = f2bf(bv.w);
    }
    __syncthreads();
    #pragma unroll
    for (int kt = 0; kt < 64; kt += 32) {
        bf16x8 af[2], bfr[2];
        #pragma unroll
        for (int mi = 0; mi < 2; mi++)
            af[mi] = *(bf16x8*)&As[(wy * 32 + mi * 16 + l16) * 72 + kt + quad * 8];
        #pragma unroll
        for (int ni = 0; ni < 2; ni++)
            bfr[ni] = *(bf16x8*)&Bs[(wx * 32 + ni * 16 + l16) * 72 + kt + quad * 8];
        #pragma unroll
        for (int mi = 0; mi < 2; mi++)
            #pragma unroll
            for (int ni = 0; ni < 2; ni++)
                acc[mi][ni] = __builtin_amdgcn_mfma_f32_16x16x32_bf16(
                    af[mi], bfr[ni], acc[mi][ni], 0, 0, 0);
    }
    #pragma unroll
    for (int mi = 0; mi < 2; mi++)
        #pragma unroll
        for (int ni = 0; ni < 2; ni++)
            #pragma unroll
            for (int e = 0; e < 4; e++) {
                const int gm = mBase + wy * 32 + mi * 16 + quad * 4 + e;
                const int gn = nBase + wx * 32 + ni * 16 + l16;
                unsafeAtomicAdd(&C[(size_t)gm * HID + gn], acc[mi][ni][e]);
            }
}

// ---------------- fused all-pairs edge network + node update (v2) ----------
// 16 lanes per edge, 4 edges per wave concurrently, LDS-compacted match list.
// 1 shfl per edge instead of 6; countable loop -> pipelined loads.
__global__ __launch_bounds__(256) void pair_update2(
    const float* __restrict__ di, const float* __restrict__ hi,
    const float* __restrict__ hj, const float* __restrict__ bwe1,
    const float* __restrict__ We2, const float* __restrict__ bwe2,
    const int* __restrict__ labels, float* __restrict__ out)
{
    __shared__ int   slab[N_PTS];
    __shared__ int   list[N_PTS];
    __shared__ int   cnt;
    __shared__ float sacc[16][HID];
    __shared__ float swsum[16];
    const int i   = blockIdx.x;
    const int tid = threadIdx.x;
    const int pid = tid >> 4;       // 16 groups of 16 lanes
    const int l16 = tid & 15;

    if (tid == 0) cnt = 0;
    for (int t = tid; t < N_PTS; t += 256) slab[t] = labels[t];
    __syncthreads();
    const int myLab = slab[i];
    for (int t = tid; t < N_PTS; t += 256)
        if (slab[t] == myLab && t != i) list[atomicAdd(&cnt, 1)] = t;
    __syncthreads();
    const int n = cnt;

    // per-lane constants: h-slice [l16*16, l16*16+16)
    const float4* hip4 = (const float4*)(hi + (size_t)i * HID) + l16 * 4;
    const float4* bw4  = (const float4*)bwe1 + l16 * 4;
    const float4* w24  = (const float4*)We2  + l16 * 4;
    float4 hb[4], w2[4];
    #pragma unroll
    for (int s = 0; s < 4; s++) {
        float4 a = hip4[s], b = bw4[s];
        hb[s] = make_float4(a.x + b.x, a.y + b.y, a.z + b.z, a.w + b.w);
        w2[s] = w24[s];
    }
    const float b2 = bwe2[0];

    float4 acc[4] = {};
    float wloc = 0.f;
    const int rounds = (n + 15) >> 4;
    for (int r = 0; r < rounds; ++r) {
        const int idx = r * 16 + pid;
        const bool valid = idx < n;
        const int jj = valid ? list[idx] : i;
        const float4* hv4 = (const float4*)(hj + (size_t)jj * HID) + l16 * 4;
        float4 hv[4];
        #pragma unroll
        for (int s = 0; s < 4; s++) hv[s] = hv4[s];
        float p = 0.f;
        #pragma unroll
        for (int s = 0; s < 4; s++) {
            p = fmaf(fmaxf(hb[s].x + hv[s].x, 0.f), w2[s].x, p);
            p = fmaf(fmaxf(hb[s].y + hv[s].y, 0.f), w2[s].y, p);
            p = fmaf(fmaxf(hb[s].z + hv[s].z, 0.f), w2[s].z, p);
            p = fmaf(fmaxf(hb[s].w + hv[s].w, 0.f), w2[s].w, p);
        }
        p += __shfl_xor(p, 1, 64);
        p += __shfl_xor(p, 2, 64);
        p += __shfl_xor(p, 4, 64);
        p += __shfl_xor(p, 8, 64);
        const float w = valid ? 1.f / (1.f + expf(-(p + b2))) : 0.f;
        const float4* dv4 = (const float4*)(di + (size_t)jj * HID) + l16 * 4;
        #pragma unroll
        for (int s = 0; s < 4; s++) {
            float4 d = dv4[s];
            acc[s].x = fmaf(w, d.x, acc[s].x);
            acc[s].y = fmaf(w, d.y, acc[s].y);
            acc[s].z = fmaf(w, d.z, acc[s].z);
            acc[s].w = fmaf(w, d.w, acc[s].w);
        }
        if (l16 == 0) wloc += w;
    }
    #pragma unroll
    for (int s = 0; s < 4; s++)
        ((float4*)&sacc[pid][l16 * 16])[s] = acc[s];
    if (l16 == 0) swsum[pid] = wloc;
    __syncthreads();

    float at = 0.f;
    #pragma unroll
    for (int g = 0; g < 16; g++) at += sacc[g][tid];
    float wt = 0.f;
    #pragma unroll
    for (int g = 0; g < 16; g++) wt += swsum[g];
    const float dval = di[(size_t)i * HID + tid];
    out[(size_t)i * HID + tid] = dval + (wt > 0.f ? at / wt : 0.f);
}

extern "C" void kernel_launch(void* const* d_in, const int* in_sizes, int n_in,
                              void* d_out, int out_size, void* d_ws, size_t ws_size,
                              hipStream_t stream)
{
    const float* features = (const float*)d_in[0];
    const int*   labels   = (const int*)d_in[1];
    const float* W1   = (const float*)d_in[2];
    // b1/b2 cancel exactly through train-mode BN (mean subtraction)
    const float* g1   = (const float*)d_in[4];
    const float* bt1  = (const float*)d_in[5];
    const float* W2   = (const float*)d_in[6];
    const float* g2   = (const float*)d_in[8];
    const float* bt2  = (const float*)d_in[9];
    const float* We1  = (const float*)d_in[10];
    const float* bwe1 = (const float*)d_in[11];
    const float* We2  = (const float*)d_in[12];
    const float* bwe2 = (const float*)d_in[13];
    float* out = (float*)d_out;

    float* ws    = (float*)d_ws;
    float* x1    = ws;                 // 262144  (atomic, zeroed)
    float* hi    = ws + 262144;        // 262144  (atomic, zeroed)
    float* hj    = ws + 524288;        // 262144  (atomic, zeroed)
    float* stats = ws + 786432;        // 1024: sum1, sq1, sum2, sq2 (zeroed)
    float* x2    = ws + 787456;        // 262144  (plain stores)
    float* di    = ws + 1049600;       // 262144  (plain stores)

    // zero only atomic-accumulated buffers: x1, hi, hj, stats
    hipMemsetAsync(d_ws, 0, 787456 * sizeof(float), stream);

    dim3 blk(256);
    // layer 1: x1 = features @ W1  [1024x2048 @ 2048x256], 8-way split-K
    gemm_mfma<<<dim3(4, 16, 8), blk, 0, stream>>>(features, W1, x1,
                                                  FEAT, HID, HID, 256);
    colstats<<<256, blk, 0, stream>>>(x1, stats, stats + 256, 4);
    // layer 2: x2 = relu(bn1(x1)) @ W2, BN1 fused into staging,
    // colstats2 fused into epilogue (split-K = 1)
    gemm2_fused<<<dim3(4, 16, 1), blk, 0, stream>>>(x1, W2, x2,
                                                    stats, stats + 256, g1, bt1,
                                                    stats + 512, stats + 768);
    bn_relu<<<256, blk, 0, stream>>>(x2, stats + 512, stats + 768, g2, bt2, di);
    // edge net halves in ONE launch: hi = di @ We1[:H], hj = di @ We1[H:]
    gemm_dual<<<dim3(4, 16, 8), blk, 0, stream>>>(di, We1, We1 + HID * HID,
                                                  hi, hj);
    // fused all-pairs edge weights + node feature update
    pair_update2<<<N_PTS, blk, 0, stream>>>(di, hi, hj, bwe1, We2, bwe2,
                                            labels, out);
}

// Round 2
// 145.402 us; speedup vs baseline: 1.1046x; 1.0665x over previous
//
#include <hip/hip_runtime.h>
#include <math.h>

#define N_PTS 1024
#define HID   256
#define FEAT  2048

typedef short bf16x8 __attribute__((ext_vector_type(8)));
typedef float f32x4  __attribute__((ext_vector_type(4)));

__device__ inline ushort f2bf(float f) {
    union { float f; unsigned u; } v; v.f = f;
    unsigned r = v.u + 0x7fff + ((v.u >> 16) & 1);   // round-to-nearest-even
    return (ushort)(r >> 16);
}

// ---------------- prep: fp32->bf16 convert + weight transposes -------------
// b < 512            : features [1024][2048] -> Af bf16 [1024][2048]
// 512 <= b < 640     : W1 [2048][256] -> W1T bf16 [256][2048]
// 640 <= b < 656     : W2 [256][256]  -> W2T bf16 [256][256]
// 656 <= b < 688     : We1 [512][256] -> WeT bf16 [256][512]
__global__ __launch_bounds__(256) void prep(
    const float* __restrict__ features, const float* __restrict__ W1,
    const float* __restrict__ W2, const float* __restrict__ We1,
    ushort* __restrict__ Af, ushort* __restrict__ W1T,
    ushort* __restrict__ W2T, ushort* __restrict__ WeT)
{
    const int tid = threadIdx.x;
    int b = blockIdx.x;
    if (b < 512) {               // straight convert, [m][k] kept
        #pragma unroll
        for (int q = 0; q < 2; q++) {
            const size_t g = (size_t)b * 256 + tid + (size_t)q * 131072;
            float4 v0 = ((const float4*)features)[g * 2];
            float4 v1 = ((const float4*)features)[g * 2 + 1];
            bf16x8 o;
            o[0] = (short)f2bf(v0.x); o[1] = (short)f2bf(v0.y);
            o[2] = (short)f2bf(v0.z); o[3] = (short)f2bf(v0.w);
            o[4] = (short)f2bf(v1.x); o[5] = (short)f2bf(v1.y);
            o[6] = (short)f2bf(v1.z); o[7] = (short)f2bf(v1.w);
            ((bf16x8*)Af)[g] = o;
        }
        return;
    }
    // 64x64 transpose tiles: src fp32 [K][256] -> dst bf16 [256][K]
    __shared__ ushort Ts[64 * 72];
    const float* src; ushort* dst; int K;
    b -= 512;
    if (b < 128)      { src = W1;  dst = W1T; K = 2048; }
    else if (b < 144) { b -= 128; src = W2;  dst = W2T; K = 256; }
    else              { b -= 144; src = We1; dst = WeT; K = 512; }
    const int k0 = (b >> 2) * 64;
    const int n0 = (b & 3) * 64;
    #pragma unroll
    for (int p = 0; p < 4; p++) {
        const int c  = p * 256 + tid;
        const int r  = c >> 4;           // k-local
        const int cq = c & 15;           // n-chunk
        float4 v = *(const float4*)&src[(size_t)(k0 + r) * 256 + n0 + cq * 4];
        Ts[(cq * 4 + 0) * 72 + r] = f2bf(v.x);
        Ts[(cq * 4 + 1) * 72 + r] = f2bf(v.y);
        Ts[(cq * 4 + 2) * 72 + r] = f2bf(v.z);
        Ts[(cq * 4 + 3) * 72 + r] = f2bf(v.w);
    }
    __syncthreads();
    #pragma unroll
    for (int p = 0; p < 2; p++) {
        const int c    = p * 256 + tid;  // 0..511
        const int row  = c >> 3;         // n-local
        const int col8 = c & 7;          // 8-wide k chunk
        *(bf16x8*)&dst[(size_t)(n0 + row) * K + k0 + col8 * 8] =
            *(bf16x8*)&Ts[row * 72 + col8 * 8];
    }
}

// ---------------- bf16-input MFMA GEMM: C += A@B^T (atomic fp32) -----------
// A bf16 [M][lda] (k-contig), B bf16 [N][ldb] (k-contig). 64x64 tile, BK=64,
// 256 threads (2x2 waves), split-K over blockIdx.z. Staging = pure 16B copies.
__global__ __launch_bounds__(256) void gemm_bf(
    const ushort* __restrict__ A, const ushort* __restrict__ B,
    float* __restrict__ C, int lda, int ldb, int ldc, int kchunk)
{
    __shared__ ushort As[64 * 72];
    __shared__ ushort Bs[64 * 72];
    const int tid  = threadIdx.x;
    const int lane = tid & 63;
    const int wave = tid >> 6;
    const int wy = wave >> 1, wx = wave & 1;
    const int quad = lane >> 4, l16 = lane & 15;
    const int mBase = blockIdx.y * 64;
    const int nBase = blockIdx.x * 64;
    const int kBeg  = blockIdx.z * kchunk;

    f32x4 acc[2][2] = {};
    for (int ks = kBeg; ks < kBeg + kchunk; ks += 64) {
        #pragma unroll
        for (int p = 0; p < 2; p++) {
            const int c    = p * 256 + tid;   // 0..511
            const int row  = c >> 3;
            const int col8 = c & 7;
            *(bf16x8*)&As[row * 72 + col8 * 8] =
                *(const bf16x8*)&A[(size_t)(mBase + row) * lda + ks + col8 * 8];
            *(bf16x8*)&Bs[row * 72 + col8 * 8] =
                *(const bf16x8*)&B[(size_t)(nBase + row) * ldb + ks + col8 * 8];
        }
        __syncthreads();
        #pragma unroll
        for (int kt = 0; kt < 64; kt += 32) {
            bf16x8 af[2], bfr[2];
            #pragma unroll
            for (int mi = 0; mi < 2; mi++)
                af[mi] = *(bf16x8*)&As[(wy * 32 + mi * 16 + l16) * 72 + kt + quad * 8];
            #pragma unroll
            for (int ni = 0; ni < 2; ni++)
                bfr[ni] = *(bf16x8*)&Bs[(wx * 32 + ni * 16 + l16) * 72 + kt + quad * 8];
            #pragma unroll
            for (int mi = 0; mi < 2; mi++)
                #pragma unroll
                for (int ni = 0; ni < 2; ni++)
                    acc[mi][ni] = __builtin_amdgcn_mfma_f32_16x16x32_bf16(
                        af[mi], bfr[ni], acc[mi][ni], 0, 0, 0);
        }
        __syncthreads();
    }
    #pragma unroll
    for (int mi = 0; mi < 2; mi++)
        #pragma unroll
        for (int ni = 0; ni < 2; ni++)
            #pragma unroll
            for (int e = 0; e < 4; e++) {
                const int gm = mBase + wy * 32 + mi * 16 + quad * 4 + e;
                const int gn = nBase + wx * 32 + ni * 16 + l16;
                unsafeAtomicAdd(&C[(size_t)gm * ldc + gn], acc[mi][ni][e]);
            }
}

// ---------------- per-column sum / sumsq for x1 (atomic partials) ----------
__global__ __launch_bounds__(256) void colstats(
    const float* __restrict__ X, float* __restrict__ sum,
    float* __restrict__ sq, int rowsPerBlock)
{
    const int c = threadIdx.x;
    const int r0 = blockIdx.x * rowsPerBlock;
    float s = 0.f, q = 0.f;
    for (int r = r0; r < r0 + rowsPerBlock; ++r) {
        float v = X[r * HID + c];
        s += v;
        q = fmaf(v, v, q);
    }
    unsafeAtomicAdd(&sum[c], s);
    unsafeAtomicAdd(&sq[c], q);
}

// ---- layer2 GEMM, split-K=1: BN1+ReLU fused into A-staging, colstats2
// ---- fused into epilogue. B pre-converted bf16 [n][k].
__global__ __launch_bounds__(256) void gemm2_fused(
    const float* __restrict__ A /*x1*/, const ushort* __restrict__ B /*W2T*/,
    float* __restrict__ C /*x2*/,
    const float* __restrict__ sum1, const float* __restrict__ sq1,
    const float* __restrict__ g1, const float* __restrict__ bt1,
    float* __restrict__ sum2, float* __restrict__ sq2)
{
    __shared__ ushort As[64 * 72];
    __shared__ ushort Bs[64 * 72];
    __shared__ float sscale[HID];
    __shared__ float sshift[HID];
    __shared__ float csum[64];
    __shared__ float csq[64];
    const int tid  = threadIdx.x;
    const int lane = tid & 63;
    const int wave = tid >> 6;
    const int wy = wave >> 1, wx = wave & 1;
    const int quad = lane >> 4, l16 = lane & 15;
    const int mBase = blockIdx.y * 64;
    const int nBase = blockIdx.x * 64;

    {
        float m   = sum1[tid] * (1.f / 1024.f);
        float var = fmaf(-m, m, sq1[tid] * (1.f / 1024.f));
        float rstd = rsqrtf(var + 1e-5f);
        float sc = g1[tid] * rstd;
        sscale[tid] = sc;
        sshift[tid] = fmaf(-m, sc, bt1[tid]);
    }
    if (tid < 64) { csum[tid] = 0.f; csq[tid] = 0.f; }
    __syncthreads();

    f32x4 acc[2][2] = {};
    for (int ks = 0; ks < HID; ks += 64) {
        #pragma unroll
        for (int p = 0; p < 4; p++) {
            const int c  = p * 256 + tid;
            const int r  = c >> 4;
            const int cq = c & 15;
            const int k0 = ks + cq * 4;
            float4 av = *(const float4*)&A[(size_t)(mBase + r) * HID + k0];
            float v0 = fmaxf(fmaf(sscale[k0 + 0], av.x, sshift[k0 + 0]), 0.f);
            float v1 = fmaxf(fmaf(sscale[k0 + 1], av.y, sshift[k0 + 1]), 0.f);
            float v2 = fmaxf(fmaf(sscale[k0 + 2], av.z, sshift[k0 + 2]), 0.f);
            float v3 = fmaxf(fmaf(sscale[k0 + 3], av.w, sshift[k0 + 3]), 0.f);
            ushort4 ao;
            ao.x = f2bf(v0); ao.y = f2bf(v1); ao.z = f2bf(v2); ao.w = f2bf(v3);
            *(ushort4*)&As[r * 72 + cq * 4] = ao;
        }
        #pragma unroll
        for (int p = 0; p < 2; p++) {
            const int c    = p * 256 + tid;
            const int row  = c >> 3;
            const int col8 = c & 7;
            *(bf16x8*)&Bs[row * 72 + col8 * 8] =
                *(const bf16x8*)&B[(size_t)(nBase + row) * HID + ks + col8 * 8];
        }
        __syncthreads();
        #pragma unroll
        for (int kt = 0; kt < 64; kt += 32) {
            bf16x8 af[2], bfr[2];
            #pragma unroll
            for (int mi = 0; mi < 2; mi++)
                af[mi] = *(bf16x8*)&As[(wy * 32 + mi * 16 + l16) * 72 + kt + quad * 8];
            #pragma unroll
            for (int ni = 0; ni < 2; ni++)
                bfr[ni] = *(bf16x8*)&Bs[(wx * 32 + ni * 16 + l16) * 72 + kt + quad * 8];
            #pragma unroll
            for (int mi = 0; mi < 2; mi++)
                #pragma unroll
                for (int ni = 0; ni < 2; ni++)
                    acc[mi][ni] = __builtin_amdgcn_mfma_f32_16x16x32_bf16(
                        af[mi], bfr[ni], acc[mi][ni], 0, 0, 0);
        }
        __syncthreads();
    }

    float s[2] = {0.f, 0.f}, q[2] = {0.f, 0.f};
    #pragma unroll
    for (int mi = 0; mi < 2; mi++)
        #pragma unroll
        for (int ni = 0; ni < 2; ni++)
            #pragma unroll
            for (int e = 0; e < 4; e++) {
                const int gm = mBase + wy * 32 + mi * 16 + quad * 4 + e;
                const int gn = nBase + wx * 32 + ni * 16 + l16;
                float v = acc[mi][ni][e];
                C[(size_t)gm * HID + gn] = v;
                s[ni] += v;
                q[ni] = fmaf(v, v, q[ni]);
            }
    #pragma unroll
    for (int ni = 0; ni < 2; ni++) {
        float sv = s[ni], qv = q[ni];
        sv += __shfl_xor(sv, 16, 64); sv += __shfl_xor(sv, 32, 64);
        qv += __shfl_xor(qv, 16, 64); qv += __shfl_xor(qv, 32, 64);
        if (quad == 0) {
            atomicAdd(&csum[wx * 32 + ni * 16 + l16], sv);
            atomicAdd(&csq [wx * 32 + ni * 16 + l16], qv);
        }
    }
    __syncthreads();
    if (tid < 64) {
        unsafeAtomicAdd(&sum2[nBase + tid], csum[tid]);
        unsafeAtomicAdd(&sq2 [nBase + tid], csq[tid]);
    }
}

// ---- merged edge-net GEMMs with BN2+ReLU fused into A-staging.
// z<4 -> hi += di@We1[:H], z>=4 -> hj += di@We1[H:].  Blocks with
// (x==0, half==0) also store fp32 di for pair_update.
__global__ __launch_bounds__(256) void gemm_dual_bn(
    const float* __restrict__ A /*x2*/, const ushort* __restrict__ WeT,
    float* __restrict__ C1 /*hi*/, float* __restrict__ C2 /*hj*/,
    const float* __restrict__ sum2, const float* __restrict__ sq2,
    const float* __restrict__ g2, const float* __restrict__ bt2,
    float* __restrict__ di)
{
    __shared__ ushort As[64 * 72];
    __shared__ ushort Bs[64 * 72];
    __shared__ float sscale[HID];
    __shared__ float sshift[HID];
    const int tid  = threadIdx.x;
    const int lane = tid & 63;
    const int wave = tid >> 6;
    const int wy = wave >> 1, wx = wave & 1;
    const int quad = lane >> 4, l16 = lane & 15;
    const int mBase = blockIdx.y * 64;
    const int nBase = blockIdx.x * 64;
    const int half  = blockIdx.z >> 2;
    const int ks    = (blockIdx.z & 3) * 64;
    float* C = half ? C2 : C1;
    const bool writeDi = (blockIdx.x == 0) && (half == 0);

    {
        float m   = sum2[tid] * (1.f / 1024.f);
        float var = fmaf(-m, m, sq2[tid] * (1.f / 1024.f));
        float rstd = rsqrtf(var + 1e-5f);
        float sc = g2[tid] * rstd;
        sscale[tid] = sc;
        sshift[tid] = fmaf(-m, sc, bt2[tid]);
    }
    __syncthreads();

    #pragma unroll
    for (int p = 0; p < 4; p++) {
        const int c  = p * 256 + tid;
        const int r  = c >> 4;
        const int cq = c & 15;
        const int k0 = ks + cq * 4;
        float4 av = *(const float4*)&A[(size_t)(mBase + r) * HID + k0];
        float v0 = fmaxf(fmaf(sscale[k0 + 0], av.x, sshift[k0 + 0]), 0.f);
        float v1 = fmaxf(fmaf(sscale[k0 + 1], av.y, sshift[k0 + 1]), 0.f);
        float v2 = fmaxf(fmaf(sscale[k0 + 2], av.z, sshift[k0 + 2]), 0.f);
        float v3 = fmaxf(fmaf(sscale[k0 + 3], av.w, sshift[k0 + 3]), 0.f);
        if (writeDi)
            *(float4*)&di[(size_t)(mBase + r) * HID + k0] =
                make_float4(v0, v1, v2, v3);
        ushort4 ao;
        ao.x = f2bf(v0); ao.y = f2bf(v1); ao.z = f2bf(v2); ao.w = f2bf(v3);
        *(ushort4*)&As[r * 72 + cq * 4] = ao;
    }
    #pragma unroll
    for (int p = 0; p < 2; p++) {
        const int c    = p * 256 + tid;
        const int row  = c >> 3;
        const int col8 = c & 7;
        *(bf16x8*)&Bs[row * 72 + col8 * 8] =
            *(const bf16x8*)&WeT[(size_t)(nBase + row) * 512 + half * 256 + ks + col8 * 8];
    }
    __syncthreads();

    f32x4 acc[2][2] = {};
    #pragma unroll
    for (int kt = 0; kt < 64; kt += 32) {
        bf16x8 af[2], bfr[2];
        #pragma unroll
        for (int mi = 0; mi < 2; mi++)
            af[mi] = *(bf16x8*)&As[(wy * 32 + mi * 16 + l16) * 72 + kt + quad * 8];
        #pragma unroll
        for (int ni = 0; ni < 2; ni++)
            bfr[ni] = *(bf16x8*)&Bs[(wx * 32 + ni * 16 + l16) * 72 + kt + quad * 8];
        #pragma unroll
        for (int mi = 0; mi < 2; mi++)
            #pragma unroll
            for (int ni = 0; ni < 2; ni++)
                acc[mi][ni] = __builtin_amdgcn_mfma_f32_16x16x32_bf16(
                    af[mi], bfr[ni], acc[mi][ni], 0, 0, 0);
    }
    #pragma unroll
    for (int mi = 0; mi < 2; mi++)
        #pragma unroll
        for (int ni = 0; ni < 2; ni++)
            #pragma unroll
            for (int e = 0; e < 4; e++) {
                const int gm = mBase + wy * 32 + mi * 16 + quad * 4 + e;
                const int gn = nBase + wx * 32 + ni * 16 + l16;
                unsafeAtomicAdd(&C[(size_t)gm * HID + gn], acc[mi][ni][e]);
            }
}

// ---------------- fused all-pairs edge network + node update ---------------
__global__ __launch_bounds__(256) void pair_update2(
    const float* __restrict__ di, const float* __restrict__ hi,
    const float* __restrict__ hj, const float* __restrict__ bwe1,
    const float* __restrict__ We2, const float* __restrict__ bwe2,
    const int* __restrict__ labels, float* __restrict__ out)
{
    __shared__ int   slab[N_PTS];
    __shared__ int   list[N_PTS];
    __shared__ int   cnt;
    __shared__ float sacc[16][HID];
    __shared__ float swsum[16];
    const int i   = blockIdx.x;
    const int tid = threadIdx.x;
    const int pid = tid >> 4;
    const int l16 = tid & 15;

    if (tid == 0) cnt = 0;
    for (int t = tid; t < N_PTS; t += 256) slab[t] = labels[t];
    __syncthreads();
    const int myLab = slab[i];
    for (int t = tid; t < N_PTS; t += 256)
        if (slab[t] == myLab && t != i) list[atomicAdd(&cnt, 1)] = t;
    __syncthreads();
    const int n = cnt;

    const float4* hip4 = (const float4*)(hi + (size_t)i * HID) + l16 * 4;
    const float4* bw4  = (const float4*)bwe1 + l16 * 4;
    const float4* w24  = (const float4*)We2  + l16 * 4;
    float4 hb[4], w2[4];
    #pragma unroll
    for (int s = 0; s < 4; s++) {
        float4 a = hip4[s], b = bw4[s];
        hb[s] = make_float4(a.x + b.x, a.y + b.y, a.z + b.z, a.w + b.w);
        w2[s] = w24[s];
    }
    const float b2 = bwe2[0];

    float4 acc[4] = {};
    float wloc = 0.f;
    const int rounds = (n + 15) >> 4;
    for (int r = 0; r < rounds; ++r) {
        const int idx = r * 16 + pid;
        const bool valid = idx < n;
        const int jj = valid ? list[idx] : i;
        const float4* hv4 = (const float4*)(hj + (size_t)jj * HID) + l16 * 4;
        float4 hv[4];
        #pragma unroll
        for (int s = 0; s < 4; s++) hv[s] = hv4[s];
        float p = 0.f;
        #pragma unroll
        for (int s = 0; s < 4; s++) {
            p = fmaf(fmaxf(hb[s].x + hv[s].x, 0.f), w2[s].x, p);
            p = fmaf(fmaxf(hb[s].y + hv[s].y, 0.f), w2[s].y, p);
            p = fmaf(fmaxf(hb[s].z + hv[s].z, 0.f), w2[s].z, p);
            p = fmaf(fmaxf(hb[s].w + hv[s].w, 0.f), w2[s].w, p);
        }
        p += __shfl_xor(p, 1, 64);
        p += __shfl_xor(p, 2, 64);
        p += __shfl_xor(p, 4, 64);
        p += __shfl_xor(p, 8, 64);
        const float w = valid ? 1.f / (1.f + expf(-(p + b2))) : 0.f;
        const float4* dv4 = (const float4*)(di + (size_t)jj * HID) + l16 * 4;
        #pragma unroll
        for (int s = 0; s < 4; s++) {
            float4 d = dv4[s];
            acc[s].x = fmaf(w, d.x, acc[s].x);
            acc[s].y = fmaf(w, d.y, acc[s].y);
            acc[s].z = fmaf(w, d.z, acc[s].z);
            acc[s].w = fmaf(w, d.w, acc[s].w);
        }
        if (l16 == 0) wloc += w;
    }
    #pragma unroll
    for (int s = 0; s < 4; s++)
        ((float4*)&sacc[pid][l16 * 16])[s] = acc[s];
    if (l16 == 0) swsum[pid] = wloc;
    __syncthreads();

    float at = 0.f;
    #pragma unroll
    for (int g = 0; g < 16; g++) at += sacc[g][tid];
    float wt = 0.f;
    #pragma unroll
    for (int g = 0; g < 16; g++) wt += swsum[g];
    const float dval = di[(size_t)i * HID + tid];
    out[(size_t)i * HID + tid] = dval + (wt > 0.f ? at / wt : 0.f);
}

extern "C" void kernel_launch(void* const* d_in, const int* in_sizes, int n_in,
                              void* d_out, int out_size, void* d_ws, size_t ws_size,
                              hipStream_t stream)
{
    const float* features = (const float*)d_in[0];
    const int*   labels   = (const int*)d_in[1];
    const float* W1   = (const float*)d_in[2];
    // b1/b2 cancel exactly through train-mode BN (mean subtraction)
    const float* g1   = (const float*)d_in[4];
    const float* bt1  = (const float*)d_in[5];
    const float* W2   = (const float*)d_in[6];
    const float* g2   = (const float*)d_in[8];
    const float* bt2  = (const float*)d_in[9];
    const float* We1  = (const float*)d_in[10];
    const float* bwe1 = (const float*)d_in[11];
    const float* We2  = (const float*)d_in[12];
    const float* bwe2 = (const float*)d_in[13];
    float* out = (float*)d_out;

    float* ws    = (float*)d_ws;
    float* x1    = ws;                 // 262144  (atomic, zeroed)
    float* hi    = ws + 262144;        // 262144  (atomic, zeroed)
    float* hj    = ws + 524288;        // 262144  (atomic, zeroed)
    float* stats = ws + 786432;        // 1024: sum1, sq1, sum2, sq2 (zeroed)
    float* x2    = ws + 787456;        // 262144  (plain stores)
    float* di    = ws + 1049600;       // 262144  (plain stores)
    ushort* Af   = (ushort*)(ws + 1311744);   // 1024*2048 bf16
    ushort* W1T  = Af + 2097152;              // 256*2048 bf16
    ushort* W2T  = W1T + 524288;              // 256*256 bf16
    ushort* WeT  = W2T + 65536;               // 256*512 bf16

    // zero only atomic-accumulated buffers: x1, hi, hj, stats
    hipMemsetAsync(d_ws, 0, 787456 * sizeof(float), stream);

    dim3 blk(256);
    // bf16 convert + weight pre-transposes
    prep<<<688, blk, 0, stream>>>(features, W1, W2, We1, Af, W1T, W2T, WeT);
    // layer 1: x1 = features @ W1  [1024x2048 @ 2048x256], 8-way split-K
    gemm_bf<<<dim3(4, 16, 8), blk, 0, stream>>>(Af, W1T, x1,
                                                FEAT, FEAT, HID, 256);
    colstats<<<256, blk, 0, stream>>>(x1, stats, stats + 256, 4);
    // layer 2: x2 = relu(bn1(x1)) @ W2, BN1 fused into staging,
    // colstats2 fused into epilogue
    gemm2_fused<<<dim3(4, 16, 1), blk, 0, stream>>>(x1, W2T, x2,
                                                    stats, stats + 256, g1, bt1,
                                                    stats + 512, stats + 768);
    // edge net halves + BN2/ReLU fused into A-staging; also emits di
    gemm_dual_bn<<<dim3(4, 16, 8), blk, 0, stream>>>(x2, WeT, hi, hj,
                                                     stats + 512, stats + 768,
                                                     g2, bt2, di);
    // fused all-pairs edge weights + node feature update
    pair_update2<<<N_PTS, blk, 0, stream>>>(di, hi, hj, bwe1, We2, bwe2,
                                            labels, out);
}

// Round 4
// 138.378 us; speedup vs baseline: 1.1607x; 1.0508x over previous
//
#include <hip/hip_runtime.h>
#include <math.h>

#define N_PTS 1024
#define HID   256
#define FEAT  2048

typedef short bf16x8 __attribute__((ext_vector_type(8)));
typedef float f32x4  __attribute__((ext_vector_type(4)));

__device__ inline ushort f2bf(float f) {
    union { float f; unsigned u; } v; v.f = f;
    unsigned r = v.u + 0x7fff + ((v.u >> 16) & 1);   // round-to-nearest-even
    return (ushort)(r >> 16);
}

// ---------------- prep: fp32->bf16 convert + weight transposes -------------
// b < 512            : features [1024][2048] -> Af bf16 [1024][2048]
//   (b == 300 also zeroes the 1024-float stats buffer)
// 512 <= b < 640     : W1 [2048][256] -> W1T bf16 [256][2048]
// 640 <= b < 656     : W2 [256][256]  -> W2T bf16 [256][256]
// 656 <= b < 688     : We1 [512][256] -> WeT bf16 [256][512]
__global__ __launch_bounds__(256) void prep(
    const float* __restrict__ features, const float* __restrict__ W1,
    const float* __restrict__ W2, const float* __restrict__ We1,
    ushort* __restrict__ Af, ushort* __restrict__ W1T,
    ushort* __restrict__ W2T, ushort* __restrict__ WeT,
    float* __restrict__ stats)
{
    const int tid = threadIdx.x;
    int b = blockIdx.x;
    if (b < 512) {               // straight convert, [m][k] kept
        if (b == 300)
            ((float4*)stats)[tid] = make_float4(0.f, 0.f, 0.f, 0.f);
        #pragma unroll
        for (int q = 0; q < 2; q++) {
            const size_t g = (size_t)b * 256 + tid + (size_t)q * 131072;
            float4 v0 = ((const float4*)features)[g * 2];
            float4 v1 = ((const float4*)features)[g * 2 + 1];
            bf16x8 o;
            o[0] = (short)f2bf(v0.x); o[1] = (short)f2bf(v0.y);
            o[2] = (short)f2bf(v0.z); o[3] = (short)f2bf(v0.w);
            o[4] = (short)f2bf(v1.x); o[5] = (short)f2bf(v1.y);
            o[6] = (short)f2bf(v1.z); o[7] = (short)f2bf(v1.w);
            ((bf16x8*)Af)[g] = o;
        }
        return;
    }
    // 64x64 transpose tiles: src fp32 [K][256] -> dst bf16 [256][K]
    __shared__ ushort Ts[64 * 72];
    const float* src; ushort* dst; int K;
    b -= 512;
    if (b < 128)      { src = W1;  dst = W1T; K = 2048; }
    else if (b < 144) { b -= 128; src = W2;  dst = W2T; K = 256; }
    else              { b -= 144; src = We1; dst = WeT; K = 512; }
    const int k0 = (b >> 2) * 64;
    const int n0 = (b & 3) * 64;
    #pragma unroll
    for (int p = 0; p < 4; p++) {
        const int c  = p * 256 + tid;
        const int r  = c >> 4;           // k-local
        const int cq = c & 15;           // n-chunk
        float4 v = *(const float4*)&src[(size_t)(k0 + r) * 256 + n0 + cq * 4];
        Ts[(cq * 4 + 0) * 72 + r] = f2bf(v.x);
        Ts[(cq * 4 + 1) * 72 + r] = f2bf(v.y);
        Ts[(cq * 4 + 2) * 72 + r] = f2bf(v.z);
        Ts[(cq * 4 + 3) * 72 + r] = f2bf(v.w);
    }
    __syncthreads();
    #pragma unroll
    for (int p = 0; p < 2; p++) {
        const int c    = p * 256 + tid;  // 0..511
        const int row  = c >> 3;         // n-local
        const int col8 = c & 7;          // 8-wide k chunk
        *(bf16x8*)&dst[(size_t)(n0 + row) * K + k0 + col8 * 8] =
            *(bf16x8*)&Ts[row * 72 + col8 * 8];
    }
}

// ---------------- gemm1: x1p[z] = Af @ W1T (k-slice z), PLAIN stores -------
// A bf16 [1024][2048] k-contig, B bf16 [256][2048] k-contig. 64x64 tile,
// BK=64, split-K=8 over blockIdx.z, each slice to its own partial buffer.
__global__ __launch_bounds__(256) void gemm1p(
    const ushort* __restrict__ A, const ushort* __restrict__ B,
    float* __restrict__ Cp)
{
    __shared__ ushort As[64 * 72];
    __shared__ ushort Bs[64 * 72];
    const int tid  = threadIdx.x;
    const int lane = tid & 63;
    const int wave = tid >> 6;
    const int wy = wave >> 1, wx = wave & 1;
    const int quad = lane >> 4, l16 = lane & 15;
    const int mBase = blockIdx.y * 64;
    const int nBase = blockIdx.x * 64;
    const int kBeg  = blockIdx.z * 256;
    float* C = Cp + (size_t)blockIdx.z * (N_PTS * HID);

    f32x4 acc[2][2] = {};
    for (int ks = kBeg; ks < kBeg + 256; ks += 64) {
        #pragma unroll
        for (int p = 0; p < 2; p++) {
            const int c    = p * 256 + tid;   // 0..511
            const int row  = c >> 3;
            const int col8 = c & 7;
            *(bf16x8*)&As[row * 72 + col8 * 8] =
                *(const bf16x8*)&A[(size_t)(mBase + row) * FEAT + ks + col8 * 8];
            *(bf16x8*)&Bs[row * 72 + col8 * 8] =
                *(const bf16x8*)&B[(size_t)(nBase + row) * FEAT + ks + col8 * 8];
        }
        __syncthreads();
        #pragma unroll
        for (int kt = 0; kt < 64; kt += 32) {
            bf16x8 af[2], bfr[2];
            #pragma unroll
            for (int mi = 0; mi < 2; mi++)
                af[mi] = *(bf16x8*)&As[(wy * 32 + mi * 16 + l16) * 72 + kt + quad * 8];
            #pragma unroll
            for (int ni = 0; ni < 2; ni++)
                bfr[ni] = *(bf16x8*)&Bs[(wx * 32 + ni * 16 + l16) * 72 + kt + quad * 8];
            #pragma unroll
            for (int mi = 0; mi < 2; mi++)
                #pragma unroll
                for (int ni = 0; ni < 2; ni++)
                    acc[mi][ni] = __builtin_amdgcn_mfma_f32_16x16x32_bf16(
                        af[mi], bfr[ni], acc[mi][ni], 0, 0, 0);
        }
        __syncthreads();
    }
    #pragma unroll
    for (int mi = 0; mi < 2; mi++)
        #pragma unroll
        for (int ni = 0; ni < 2; ni++)
            #pragma unroll
            for (int e = 0; e < 4; e++) {
                const int gm = mBase + wy * 32 + mi * 16 + quad * 4 + e;
                const int gn = nBase + wx * 32 + ni * 16 + l16;
                C[(size_t)gm * HID + gn] = acc[mi][ni][e];
            }
}

// ---- reduce split-K partials -> x1, fused per-column sum/sumsq ----------
__global__ __launch_bounds__(256) void reduce_stats(
    const float* __restrict__ Xp, float* __restrict__ X,
    float* __restrict__ sum, float* __restrict__ sq)
{
    const int c = threadIdx.x;
    const int r0 = blockIdx.x * 4;
    float s = 0.f, q = 0.f;
    for (int r = r0; r < r0 + 4; ++r) {
        float v = 0.f;
        #pragma unroll
        for (int z = 0; z < 8; z++)
            v += Xp[(size_t)z * (N_PTS * HID) + r * HID + c];
        X[r * HID + c] = v;
        s += v;
        q = fmaf(v, v, q);
    }
    unsafeAtomicAdd(&sum[c], s);
    unsafeAtomicAdd(&sq[c], q);
}

// ---- layer2 GEMM, full K: BN1+ReLU fused into A-staging, colstats2
// ---- fused into epilogue. B pre-converted bf16 [n][k].
__global__ __launch_bounds__(256) void gemm2_fused(
    const float* __restrict__ A /*x1*/, const ushort* __restrict__ B /*W2T*/,
    float* __restrict__ C /*x2*/,
    const float* __restrict__ sum1, const float* __restrict__ sq1,
    const float* __restrict__ g1, const float* __restrict__ bt1,
    float* __restrict__ sum2, float* __restrict__ sq2)
{
    __shared__ ushort As[64 * 72];
    __shared__ ushort Bs[64 * 72];
    __shared__ float sscale[HID];
    __shared__ float sshift[HID];
    __shared__ float csum[64];
    __shared__ float csq[64];
    const int tid  = threadIdx.x;
    const int lane = tid & 63;
    const int wave = tid >> 6;
    const int wy = wave >> 1, wx = wave & 1;
    const int quad = lane >> 4, l16 = lane & 15;
    const int mBase = blockIdx.y * 64;
    const int nBase = blockIdx.x * 64;

    {
        float m   = sum1[tid] * (1.f / 1024.f);
        float var = fmaf(-m, m, sq1[tid] * (1.f / 1024.f));
        float rstd = rsqrtf(var + 1e-5f);
        float sc = g1[tid] * rstd;
        sscale[tid] = sc;
        sshift[tid] = fmaf(-m, sc, bt1[tid]);
    }
    if (tid < 64) { csum[tid] = 0.f; csq[tid] = 0.f; }
    __syncthreads();

    f32x4 acc[2][2] = {};
    for (int ks = 0; ks < HID; ks += 64) {
        #pragma unroll
        for (int p = 0; p < 4; p++) {
            const int c  = p * 256 + tid;
            const int r  = c >> 4;
            const int cq = c & 15;
            const int k0 = ks + cq * 4;
            float4 av = *(const float4*)&A[(size_t)(mBase + r) * HID + k0];
            float v0 = fmaxf(fmaf(sscale[k0 + 0], av.x, sshift[k0 + 0]), 0.f);
            float v1 = fmaxf(fmaf(sscale[k0 + 1], av.y, sshift[k0 + 1]), 0.f);
            float v2 = fmaxf(fmaf(sscale[k0 + 2], av.z, sshift[k0 + 2]), 0.f);
            float v3 = fmaxf(fmaf(sscale[k0 + 3], av.w, sshift[k0 + 3]), 0.f);
            ushort4 ao;
            ao.x = f2bf(v0); ao.y = f2bf(v1); ao.z = f2bf(v2); ao.w = f2bf(v3);
            *(ushort4*)&As[r * 72 + cq * 4] = ao;
        }
        #pragma unroll
        for (int p = 0; p < 2; p++) {
            const int c    = p * 256 + tid;
            const int row  = c >> 3;
            const int col8 = c & 7;
            *(bf16x8*)&Bs[row * 72 + col8 * 8] =
                *(const bf16x8*)&B[(size_t)(nBase + row) * HID + ks + col8 * 8];
        }
        __syncthreads();
        #pragma unroll
        for (int kt = 0; kt < 64; kt += 32) {
            bf16x8 af[2], bfr[2];
            #pragma unroll
            for (int mi = 0; mi < 2; mi++)
                af[mi] = *(bf16x8*)&As[(wy * 32 + mi * 16 + l16) * 72 + kt + quad * 8];
            #pragma unroll
            for (int ni = 0; ni < 2; ni++)
                bfr[ni] = *(bf16x8*)&Bs[(wx * 32 + ni * 16 + l16) * 72 + kt + quad * 8];
            #pragma unroll
            for (int mi = 0; mi < 2; mi++)
                #pragma unroll
                for (int ni = 0; ni < 2; ni++)
                    acc[mi][ni] = __builtin_amdgcn_mfma_f32_16x16x32_bf16(
                        af[mi], bfr[ni], acc[mi][ni], 0, 0, 0);
        }
        __syncthreads();
    }

    float s[2] = {0.f, 0.f}, q[2] = {0.f, 0.f};
    #pragma unroll
    for (int mi = 0; mi < 2; mi++)
        #pragma unroll
        for (int ni = 0; ni < 2; ni++)
            #pragma unroll
            for (int e = 0; e < 4; e++) {
                const int gm = mBase + wy * 32 + mi * 16 + quad * 4 + e;
                const int gn = nBase + wx * 32 + ni * 16 + l16;
                float v = acc[mi][ni][e];
                C[(size_t)gm * HID + gn] = v;
                s[ni] += v;
                q[ni] = fmaf(v, v, q[ni]);
            }
    #pragma unroll
    for (int ni = 0; ni < 2; ni++) {
        float sv = s[ni], qv = q[ni];
        sv += __shfl_xor(sv, 16, 64); sv += __shfl_xor(sv, 32, 64);
        qv += __shfl_xor(qv, 16, 64); qv += __shfl_xor(qv, 32, 64);
        if (quad == 0) {
            atomicAdd(&csum[wx * 32 + ni * 16 + l16], sv);
            atomicAdd(&csq [wx * 32 + ni * 16 + l16], qv);
        }
    }
    __syncthreads();
    if (tid < 64) {
        unsafeAtomicAdd(&sum2[nBase + tid], csum[tid]);
        unsafeAtomicAdd(&sq2 [nBase + tid], csq[tid]);
    }
}

// ---- dual edge GEMM, full K (no split, PLAIN stores), BN2+ReLU fused into
// ---- A-staging. z = half selects We1 half / output. (x==0,half==0) blocks
// ---- also emit fp32 di.
__global__ __launch_bounds__(256) void gemm_dual_bn(
    const float* __restrict__ A /*x2*/, const ushort* __restrict__ WeT,
    float* __restrict__ C1 /*hi*/, float* __restrict__ C2 /*hj*/,
    const float* __restrict__ sum2, const float* __restrict__ sq2,
    const float* __restrict__ g2, const float* __restrict__ bt2,
    float* __restrict__ di)
{
    __shared__ ushort As[64 * 72];
    __shared__ ushort Bs[64 * 72];
    __shared__ float sscale[HID];
    __shared__ float sshift[HID];
    const int tid  = threadIdx.x;
    const int lane = tid & 63;
    const int wave = tid >> 6;
    const int wy = wave >> 1, wx = wave & 1;
    const int quad = lane >> 4, l16 = lane & 15;
    const int mBase = blockIdx.y * 64;
    const int nBase = blockIdx.x * 64;
    const int half  = blockIdx.z;
    float* C = half ? C2 : C1;
    const bool writeDi = (blockIdx.x == 0) && (half == 0);

    {
        float m   = sum2[tid] * (1.f / 1024.f);
        float var = fmaf(-m, m, sq2[tid] * (1.f / 1024.f));
        float rstd = rsqrtf(var + 1e-5f);
        float sc = g2[tid] * rstd;
        sscale[tid] = sc;
        sshift[tid] = fmaf(-m, sc, bt2[tid]);
    }
    __syncthreads();

    f32x4 acc[2][2] = {};
    for (int ks = 0; ks < HID; ks += 64) {
        #pragma unroll
        for (int p = 0; p < 4; p++) {
            const int c  = p * 256 + tid;
            const int r  = c >> 4;
            const int cq = c & 15;
            const int k0 = ks + cq * 4;
            float4 av = *(const float4*)&A[(size_t)(mBase + r) * HID + k0];
            float v0 = fmaxf(fmaf(sscale[k0 + 0], av.x, sshift[k0 + 0]), 0.f);
            float v1 = fmaxf(fmaf(sscale[k0 + 1], av.y, sshift[k0 + 1]), 0.f);
            float v2 = fmaxf(fmaf(sscale[k0 + 2], av.z, sshift[k0 + 2]), 0.f);
            float v3 = fmaxf(fmaf(sscale[k0 + 3], av.w, sshift[k0 + 3]), 0.f);
            if (writeDi)
                *(float4*)&di[(size_t)(mBase + r) * HID + k0] =
                    make_float4(v0, v1, v2, v3);
            ushort4 ao;
            ao.x = f2bf(v0); ao.y = f2bf(v1); ao.z = f2bf(v2); ao.w = f2bf(v3);
            *(ushort4*)&As[r * 72 + cq * 4] = ao;
        }
        #pragma unroll
        for (int p = 0; p < 2; p++) {
            const int c    = p * 256 + tid;
            const int row  = c >> 3;
            const int col8 = c & 7;
            *(bf16x8*)&Bs[row * 72 + col8 * 8] =
                *(const bf16x8*)&WeT[(size_t)(nBase + row) * 512 + half * 256 + ks + col8 * 8];
        }
        __syncthreads();
        #pragma unroll
        for (int kt = 0; kt < 64; kt += 32) {
            bf16x8 af[2], bfr[2];
            #pragma unroll
            for (int mi = 0; mi < 2; mi++)
                af[mi] = *(bf16x8*)&As[(wy * 32 + mi * 16 + l16) * 72 + kt + quad * 8];
            #pragma unroll
            for (int ni = 0; ni < 2; ni++)
                bfr[ni] = *(bf16x8*)&Bs[(wx * 32 + ni * 16 + l16) * 72 + kt + quad * 8];
            #pragma unroll
            for (int mi = 0; mi < 2; mi++)
                #pragma unroll
                for (int ni = 0; ni < 2; ni++)
                    acc[mi][ni] = __builtin_amdgcn_mfma_f32_16x16x32_bf16(
                        af[mi], bfr[ni], acc[mi][ni], 0, 0, 0);
        }
        __syncthreads();
    }
    #pragma unroll
    for (int mi = 0; mi < 2; mi++)
        #pragma unroll
        for (int ni = 0; ni < 2; ni++)
            #pragma unroll
            for (int e = 0; e < 4; e++) {
                const int gm = mBase + wy * 32 + mi * 16 + quad * 4 + e;
                const int gn = nBase + wx * 32 + ni * 16 + l16;
                C[(size_t)gm * HID + gn] = acc[mi][ni][e];
            }
}

// ---------------- fused all-pairs edge network + node update ---------------
__global__ __launch_bounds__(256) void pair_update2(
    const float* __restrict__ di, const float* __restrict__ hi,
    const float* __restrict__ hj, const float* __restrict__ bwe1,
    const float* __restrict__ We2, const float* __restrict__ bwe2,
    const int* __restrict__ labels, float* __restrict__ out)
{
    __shared__ int   slab[N_PTS];
    __shared__ int   list[N_PTS];
    __shared__ int   cnt;
    __shared__ float sacc[16][HID];
    __shared__ float swsum[16];
    const int i   = blockIdx.x;
    const int tid = threadIdx.x;
    const int pid = tid >> 4;
    const int l16 = tid & 15;

    if (tid == 0) cnt = 0;
    for (int t = tid; t < N_PTS; t += 256) slab[t] = labels[t];
    __syncthreads();
    const int myLab = slab[i];
    for (int t = tid; t < N_PTS; t += 256)
        if (slab[t] == myLab && t != i) list[atomicAdd(&cnt, 1)] = t;
    __syncthreads();
    const int n = cnt;

    const float4* hip4 = (const float4*)(hi + (size_t)i * HID) + l16 * 4;
    const float4* bw4  = (const float4*)bwe1 + l16 * 4;
    const float4* w24  = (const float4*)We2  + l16 * 4;
    float4 hb[4], w2[4];
    #pragma unroll
    for (int s = 0; s < 4; s++) {
        float4 a = hip4[s], b = bw4[s];
        hb[s] = make_float4(a.x + b.x, a.y + b.y, a.z + b.z, a.w + b.w);
        w2[s] = w24[s];
    }
    const float b2 = bwe2[0];

    float4 acc[4] = {};
    float wloc = 0.f;
    const int rounds = (n + 15) >> 4;
    for (int r = 0; r < rounds; ++r) {
        const int idx = r * 16 + pid;
        const bool valid = idx < n;
        const int jj = valid ? list[idx] : i;
        const float4* hv4 = (const float4*)(hj + (size_t)jj * HID) + l16 * 4;
        float4 hv[4];
        #pragma unroll
        for (int s = 0; s < 4; s++) hv[s] = hv4[s];
        float p = 0.f;
        #pragma unroll
        for (int s = 0; s < 4; s++) {
            p = fmaf(fmaxf(hb[s].x + hv[s].x, 0.f), w2[s].x, p);
            p = fmaf(fmaxf(hb[s].y + hv[s].y, 0.f), w2[s].y, p);
            p = fmaf(fmaxf(hb[s].z + hv[s].z, 0.f), w2[s].z, p);
            p = fmaf(fmaxf(hb[s].w + hv[s].w, 0.f), w2[s].w, p);
        }
        p += __shfl_xor(p, 1, 64);
        p += __shfl_xor(p, 2, 64);
        p += __shfl_xor(p, 4, 64);
        p += __shfl_xor(p, 8, 64);
        const float w = valid ? 1.f / (1.f + expf(-(p + b2))) : 0.f;
        const float4* dv4 = (const float4*)(di + (size_t)jj * HID) + l16 * 4;
        #pragma unroll
        for (int s = 0; s < 4; s++) {
            float4 d = dv4[s];
            acc[s].x = fmaf(w, d.x, acc[s].x);
            acc[s].y = fmaf(w, d.y, acc[s].y);
            acc[s].z = fmaf(w, d.z, acc[s].z);
            acc[s].w = fmaf(w, d.w, acc[s].w);
        }
        if (l16 == 0) wloc += w;
    }
    #pragma unroll
    for (int s = 0; s < 4; s++)
        ((float4*)&sacc[pid][l16 * 16])[s] = acc[s];
    if (l16 == 0) swsum[pid] = wloc;
    __syncthreads();

    float at = 0.f;
    #pragma unroll
    for (int g = 0; g < 16; g++) at += sacc[g][tid];
    float wt = 0.f;
    #pragma unroll
    for (int g = 0; g < 16; g++) wt += swsum[g];
    const float dval = di[(size_t)i * HID + tid];
    out[(size_t)i * HID + tid] = dval + (wt > 0.f ? at / wt : 0.f);
}

extern "C" void kernel_launch(void* const* d_in, const int* in_sizes, int n_in,
                              void* d_out, int out_size, void* d_ws, size_t ws_size,
                              hipStream_t stream)
{
    const float* features = (const float*)d_in[0];
    const int*   labels   = (const int*)d_in[1];
    const float* W1   = (const float*)d_in[2];
    // b1/b2 cancel exactly through train-mode BN (mean subtraction)
    const float* g1   = (const float*)d_in[4];
    const float* bt1  = (const float*)d_in[5];
    const float* W2   = (const float*)d_in[6];
    const float* g2   = (const float*)d_in[8];
    const float* bt2  = (const float*)d_in[9];
    const float* We1  = (const float*)d_in[10];
    const float* bwe1 = (const float*)d_in[11];
    const float* We2  = (const float*)d_in[12];
    const float* bwe2 = (const float*)d_in[13];
    float* out = (float*)d_out;

    float* ws    = (float*)d_ws;
    float* x1    = ws;                 // 262144  (plain stores)
    float* hi    = ws + 262144;        // 262144  (plain stores)
    float* hj    = ws + 524288;        // 262144  (plain stores)
    float* stats = ws + 786432;        // 1024: sum1, sq1, sum2, sq2 (zeroed in prep)
    float* x2    = ws + 787456;        // 262144  (plain stores)
    float* di    = ws + 1049600;       // 262144  (plain stores)
    float* x1p   = ws + 1311744;       // 8 x 262144 split-K partials
    ushort* Af   = (ushort*)(ws + 3408896);   // 1024*2048 bf16
    ushort* W1T  = Af + 2097152;              // 256*2048 bf16
    ushort* W2T  = W1T + 524288;              // 256*256 bf16
    ushort* WeT  = W2T + 65536;               // 256*512 bf16

    dim3 blk(256);
    // bf16 convert + weight pre-transposes (+ stats zeroing in block 300)
    prep<<<688, blk, 0, stream>>>(features, W1, W2, We1, Af, W1T, W2T, WeT,
                                  stats);
    // layer 1: x1p[z] = Af @ W1T slice, 8-way split-K, plain stores
    gemm1p<<<dim3(4, 16, 8), blk, 0, stream>>>(Af, W1T, x1p);
    // sum partials -> x1, fused colstats1
    reduce_stats<<<256, blk, 0, stream>>>(x1p, x1, stats, stats + 256);
    // layer 2: x2 = relu(bn1(x1)) @ W2, BN1 fused into staging,
    // colstats2 fused into epilogue
    gemm2_fused<<<dim3(4, 16, 1), blk, 0, stream>>>(x1, W2T, x2,
                                                    stats, stats + 256, g1, bt1,
                                                    stats + 512, stats + 768);
    // edge net halves + BN2/ReLU fused into A-staging; full-K, plain stores
    gemm_dual_bn<<<dim3(4, 16, 2), blk, 0, stream>>>(x2, WeT, hi, hj,
                                                     stats + 512, stats + 768,
                                                     g2, bt2, di);
    // fused all-pairs edge weights + node feature update
    pair_update2<<<N_PTS, blk, 0, stream>>>(di, hi, hj, bwe1, We2, bwe2,
                                            labels, out);
}